// Round 8
// baseline (113.385 us; speedup 1.0000x reference)
//
#include <hip/hip_runtime.h>
#include <math.h>

// CoordinateDecoder, fully fused single kernel (R8).
// f16 MFMA (v_mfma_f32_32x32x16_f16) with the k-axis permutation trick:
//   pi(16kt+8q+reg) = 32(kt>>1)+16(kt&1)+8(reg>>2)+4q+(reg&3)
// chosen so the MFMA C/D register layout IS the next layer's B-fragment
// layout -> layer transition = lrelu + cvt_pkrtz only (no cross-lane ops).
// sqrt(2) of fused_lrelu folded into next layer's pixel-half weights.
// R8: prep fused in — each block packs the weight A-fragments into LDS
// (L2-hot broadcast reads) and computes its batch's cond-bias dots; removes
// the prep launch + graph dependency. d_ws unused.

typedef _Float16 half2v __attribute__((ext_vector_type(2)));
typedef __fp16   fp16x2 __attribute__((ext_vector_type(2)));
typedef _Float16 half4v __attribute__((ext_vector_type(4)));
typedef _Float16 half8  __attribute__((ext_vector_type(8)));
typedef float f32x16 __attribute__((ext_vector_type(16)));

#define SCALE1 0.0790569415042094833f  // 1/sqrt(160)
#define SCALE2 0.0721687836487032206f  // 1/sqrt(192)
#define SQRT2F 1.41421356237309515f

// fragment entries (half8 units): tile entry = (mt*Kt+kt)*64 + lane
#define FE_L1 0      // Mt=2, Kt=2 -> 4*64
#define FE_L2 256    // Mt=2, Kt=4 -> 8*64
#define FE_L3 768    // Mt=2, Kt=4 -> 8*64
#define FE_L4 1280   // Mt=1, Kt=4 -> 4*64 (rows j>=4 zero)
#define FE_TOT 1536  // 24576 B

__global__ __launch_bounds__(256, 4) void decoder_fused(
    const float2* __restrict__ coords,
    const float* __restrict__ c, const float* __restrict__ fu,
    const float* __restrict__ w1, const float* __restrict__ b1,
    const float* __restrict__ w2, const float* __restrict__ b2,
    const float* __restrict__ w3, const float* __restrict__ b3,
    const float* __restrict__ w4, const float* __restrict__ b4,
    float4* __restrict__ out)
{
  __shared__ __align__(16) _Float16 sfr_raw[FE_TOT * 8];  // 24576 B
  __shared__ __align__(16) float scb[196];                // cb1|cb2|cb3|cb4
  half8* __restrict__ sfr = (half8*)sfr_raw;

  const int tid  = threadIdx.x;
  const int bpx  = blockIdx.x * 256;   // block pixel base
  const int b    = bpx >> 16;          // batch image (block-uniform)

  // ================= phase 1a: pack weight A-fragments into LDS ==========
  const float freq_unlock = fu[0];
  auto pack = [&](int idx, const float* __restrict__ w, float scale,
                  int stride, bool perm, bool isL1, bool isL4, int Ktm,
                  int ebase) {
    const int til = idx >> 6, le = idx & 63, q = le >> 5;
    const int mt = til / Ktm, kt = til - mt * Ktm;
    const int j = 32 * mt + (le & 31);
    const int kbase = perm ? (32 * (kt >> 1) + 16 * (kt & 1) + 4 * q)
                           : (16 * kt + 8 * q);
    half8 v;
    if (isL4 && j >= 4) {
      #pragma unroll
      for (int r = 0; r < 8; ++r) v[r] = (_Float16)0.0f;
    } else {
      const float4 lo = *(const float4*)(w + j * stride + kbase);
      const float4 up = *(const float4*)(w + j * stride + kbase + (perm ? 8 : 4));
      float vals[8] = {lo.x, lo.y, lo.z, lo.w, up.x, up.y, up.z, up.w};
      #pragma unroll
      for (int r = 0; r < 8; ++r) {
        float s = scale;
        if (isL1) {
          const int k = kbase + r;  // identity order
          float mw = (freq_unlock - (float)((k >> 2) + 1) * (1.0f / 9.0f)) * 9.0f;
          s *= fminf(fmaxf(mw, 0.0f), 1.0f);
        }
        v[r] = (_Float16)(vals[r] * s);
      }
    }
    sfr[ebase + idx] = v;
  };
  // e = tid + 256*i maps each i to exactly one region (no divergence)
  pack(tid,       w1, SCALE1,          160, false, true,  false, 2, FE_L1);
  pack(tid,       w2, SCALE2 * SQRT2F, 192, true,  false, false, 4, FE_L2);
  pack(tid + 256, w2, SCALE2 * SQRT2F, 192, true,  false, false, 4, FE_L2);
  pack(tid,       w3, SCALE2 * SQRT2F, 192, true,  false, false, 4, FE_L3);
  pack(tid + 256, w3, SCALE2 * SQRT2F, 192, true,  false, false, 4, FE_L3);
  pack(tid,       w4, SCALE2 * SQRT2F, 192, true,  false, true,  4, FE_L4);

  // ================= phase 1b: cond-bias dots for this batch =============
  if (tid < 196) {
    const float* wr; float bias, scl;
    if (tid < 192) {
      const int grp = tid >> 6, j = tid & 63;
      if (grp == 0)      { wr = w1 + j * 160 + 32; bias = b1[j]; scl = SCALE1; }
      else if (grp == 1) { wr = w2 + j * 192 + 64; bias = b2[j]; scl = SCALE2; }
      else               { wr = w3 + j * 192 + 64; bias = b3[j]; scl = SCALE2; }
    } else {
      const int j = tid - 192;
      wr = w4 + j * 192 + 64; bias = b4[j]; scl = SCALE2;
    }
    const float4* wv = (const float4*)wr;
    const float4* cv = (const float4*)(c + b * 128);
    float4 s4 = make_float4(0.f, 0.f, 0.f, 0.f);
    #pragma unroll
    for (int k = 0; k < 32; ++k) {
      const float4 a = wv[k], d = cv[k];
      s4.x = fmaf(a.x, d.x, s4.x);
      s4.y = fmaf(a.y, d.y, s4.y);
      s4.z = fmaf(a.z, d.z, s4.z);
      s4.w = fmaf(a.w, d.w, s4.w);
    }
    scb[tid] = fmaf(scl, (s4.x + s4.y) + (s4.z + s4.w), bias);
  }
  __syncthreads();

  // ================= phase 2: MLP via MFMA ===============================
  const int lane = tid & 63;
  const int wave = tid >> 6;
  const int base = bpx + wave * 64;    // 64 px per wave
  const int col  = lane & 31;
  const bool hi  = lane >= 32;
  const int q4   = hi ? 4 : 0;

  const float* __restrict__ cb1 = scb;
  const float* __restrict__ cb2 = scb + 64;
  const float* __restrict__ cb3 = scb + 128;
  const float* __restrict__ cb4 = scb + 192;

  const int p0 = base + col, p1 = base + 32 + col;
  const float2 cc0 = coords[p0];
  const float2 cc1 = coords[p1];

  // layer-1 B fragments: sinusoidal embedding in-register
  // channel = 16kt+8q+r; (r&3): [sin x, sin y, cos x, cos y];
  // freq exponent f = 4kt+2q+(r>>2); angle = coord*0.1*2^f
  half8 bf[2][2];
  {
    const float qm = hi ? 0.4f : 0.1f;
    const float xs0 = cc0.x * qm, ys0 = cc0.y * qm;
    const float xs1 = cc1.x * qm, ys1 = cc1.y * qm;
    #pragma unroll
    for (int kt = 0; kt < 2; ++kt) {
      #pragma unroll
      for (int r = 0; r < 8; ++r) {
        const float mul = (float)(1 << (4 * kt + (r >> 2)));
        float a0, a1;
        if      ((r & 3) == 0) { a0 = __sinf(xs0 * mul); a1 = __sinf(xs1 * mul); }
        else if ((r & 3) == 1) { a0 = __sinf(ys0 * mul); a1 = __sinf(ys1 * mul); }
        else if ((r & 3) == 2) { a0 = __cosf(xs0 * mul); a1 = __cosf(xs1 * mul); }
        else                   { a0 = __cosf(ys0 * mul); a1 = __cosf(ys1 * mul); }
        bf[0][kt][r] = (_Float16)a0;
        bf[1][kt][r] = (_Float16)a1;
      }
    }
  }

  f32x16 acc[2][2];  // [mt][nt]
  half8 nbf[2][4];   // [nt][kt]

  auto lrelu = [](float v) { return fmaxf(v, 0.2f * v); };

  auto transition = [&]() {
    #pragma unroll
    for (int mt = 0; mt < 2; ++mt)
      #pragma unroll
      for (int nt = 0; nt < 2; ++nt) {
        #pragma unroll
        for (int h = 0; h < 2; ++h) {
          half2v pp[4];
          #pragma unroll
          for (int p = 0; p < 4; ++p) {
            fp16x2 t = __builtin_amdgcn_cvt_pkrtz(
                lrelu(acc[mt][nt][8 * h + 2 * p]),
                lrelu(acc[mt][nt][8 * h + 2 * p + 1]));
            pp[p] = __builtin_bit_cast(half2v, t);
          }
          half4v q0 = __builtin_shufflevector(pp[0], pp[1], 0, 1, 2, 3);
          half4v q1 = __builtin_shufflevector(pp[2], pp[3], 0, 1, 2, 3);
          nbf[nt][2 * mt + h] = __builtin_shufflevector(q0, q1, 0, 1, 2, 3, 4, 5, 6, 7);
        }
      }
  };

  auto init_acc = [&](const float* __restrict__ cb) {
    #pragma unroll
    for (int mt = 0; mt < 2; ++mt)
      #pragma unroll
      for (int g = 0; g < 4; ++g) {
        const float4 f = *(const float4*)(cb + 32 * mt + 8 * g + q4);
        acc[mt][0][4 * g + 0] = f.x; acc[mt][1][4 * g + 0] = f.x;
        acc[mt][0][4 * g + 1] = f.y; acc[mt][1][4 * g + 1] = f.y;
        acc[mt][0][4 * g + 2] = f.z; acc[mt][1][4 * g + 2] = f.z;
        acc[mt][0][4 * g + 3] = f.w; acc[mt][1][4 * g + 3] = f.w;
      }
  };

  // ---- layer 1: K=32 (Kt=2) ----
  init_acc(cb1);
  #pragma unroll
  for (int kt = 0; kt < 2; ++kt) {
    half8 a0 = sfr[FE_L1 + (0 * 2 + kt) * 64 + lane];
    half8 a1 = sfr[FE_L1 + (1 * 2 + kt) * 64 + lane];
    acc[0][0] = __builtin_amdgcn_mfma_f32_32x32x16_f16(a0, bf[0][kt], acc[0][0], 0, 0, 0);
    acc[0][1] = __builtin_amdgcn_mfma_f32_32x32x16_f16(a0, bf[1][kt], acc[0][1], 0, 0, 0);
    acc[1][0] = __builtin_amdgcn_mfma_f32_32x32x16_f16(a1, bf[0][kt], acc[1][0], 0, 0, 0);
    acc[1][1] = __builtin_amdgcn_mfma_f32_32x32x16_f16(a1, bf[1][kt], acc[1][1], 0, 0, 0);
  }
  transition();

  // ---- layers 2,3: K=64 (Kt=4) ----
  #pragma unroll
  for (int layer = 0; layer < 2; ++layer) {
    const int fe = layer == 0 ? FE_L2 : FE_L3;
    init_acc(layer == 0 ? cb2 : cb3);
    #pragma unroll
    for (int kt = 0; kt < 4; ++kt) {
      half8 a0 = sfr[fe + (0 * 4 + kt) * 64 + lane];
      half8 a1 = sfr[fe + (1 * 4 + kt) * 64 + lane];
      acc[0][0] = __builtin_amdgcn_mfma_f32_32x32x16_f16(a0, nbf[0][kt], acc[0][0], 0, 0, 0);
      acc[0][1] = __builtin_amdgcn_mfma_f32_32x32x16_f16(a0, nbf[1][kt], acc[0][1], 0, 0, 0);
      acc[1][0] = __builtin_amdgcn_mfma_f32_32x32x16_f16(a1, nbf[0][kt], acc[1][0], 0, 0, 0);
      acc[1][1] = __builtin_amdgcn_mfma_f32_32x32x16_f16(a1, nbf[1][kt], acc[1][1], 0, 0, 0);
    }
    transition();
  }

  // ---- layer 4: 64 -> 4 ----
  f32x16 acc4[2];
  {
    const float c0 = cb4[0], c1 = cb4[1], c2 = cb4[2], c3 = cb4[3];
    #pragma unroll
    for (int r = 0; r < 16; ++r) { acc4[0][r] = 0.f; acc4[1][r] = 0.f; }
    if (!hi) {
      acc4[0][0] = c0; acc4[0][1] = c1; acc4[0][2] = c2; acc4[0][3] = c3;
      acc4[1][0] = c0; acc4[1][1] = c1; acc4[1][2] = c2; acc4[1][3] = c3;
    }
  }
  #pragma unroll
  for (int kt = 0; kt < 4; ++kt) {
    half8 a0 = sfr[FE_L4 + kt * 64 + lane];
    acc4[0] = __builtin_amdgcn_mfma_f32_32x32x16_f16(a0, nbf[0][kt], acc4[0], 0, 0, 0);
    acc4[1] = __builtin_amdgcn_mfma_f32_32x32x16_f16(a0, nbf[1][kt], acc4[1], 0, 0, 0);
  }

  // epilogue: lanes 0..31 hold channels j=0..3 in regs 0..3
  if (!hi) {
    #pragma unroll
    for (int nt = 0; nt < 2; ++nt) {
      const float2 cc = nt ? cc1 : cc0;
      const float rad = sqrtf(cc.x * cc.x + cc.y * cc.y);
      const float tt = fmaxf(rad - 1.0f, 0.0f);
      const float m = 2.0f / (__expf(2.0f * tt) + 1.0f);
      out[nt ? p1 : p0] = make_float4(acc4[nt][0] * m, acc4[nt][1] * m,
                                      acc4[nt][2] * m, acc4[nt][3] * m);
    }
  }
}

extern "C" void kernel_launch(void* const* d_in, const int* in_sizes, int n_in,
                              void* d_out, int out_size, void* d_ws, size_t ws_size,
                              hipStream_t stream) {
  const float* coords = (const float*)d_in[0];
  const float* c      = (const float*)d_in[1];
  const float* fu     = (const float*)d_in[2];
  const float* w1     = (const float*)d_in[3];
  const float* b1     = (const float*)d_in[4];
  const float* w2     = (const float*)d_in[5];
  const float* b2     = (const float*)d_in[6];
  const float* w3     = (const float*)d_in[7];
  const float* b3     = (const float*)d_in[8];
  const float* w4     = (const float*)d_in[9];
  const float* b4     = (const float*)d_in[10];
  float* out = (float*)d_out;

  int npix = in_sizes[0] / 2;  // 8*256*256 = 524288

  decoder_fused<<<npix / 256, 256, 0, stream>>>(
      (const float2*)coords, c, fu, w1, b1, w2, b2, w3, b3, w4, b4,
      (float4*)out);
}

// Round 9
// 96.186 us; speedup vs baseline: 1.1788x; 1.1788x over previous
//
#include <hip/hip_runtime.h>
#include <math.h>

// CoordinateDecoder via f16 MFMA (v_mfma_f32_32x32x16_f16).
// R9 = R7 two-kernel structure (R8 per-block prep fusion regressed) +
//  (a) double-angle recurrence for the sinusoidal embedding (2 trans + 5
//      doublings per axis-pixel instead of 16 quarter-rate sin/cos),
//  (b) packed-f16 lrelu in transitions (cvt_pkrtz raw, then v_pk_mul_f16 +
//      v_pk_max_f16 on half8), ~-380 VALU cyc/wave.
// k-axis permutation trick: pi(16kt+8q+reg)=32(kt>>1)+16(kt&1)+8(reg>>2)+4q+(reg&3)
// makes the C/D register layout equal the next layer's B-fragment layout ->
// no cross-lane ops between layers. sqrt(2) folded into next-layer weights;
// cond halves precomputed as fp32 accumulator-init biases.

typedef _Float16 half2v __attribute__((ext_vector_type(2)));
typedef __fp16   fp16x2 __attribute__((ext_vector_type(2)));
typedef _Float16 half4v __attribute__((ext_vector_type(4)));
typedef _Float16 half8  __attribute__((ext_vector_type(8)));
typedef float f32x16 __attribute__((ext_vector_type(16)));

#define SCALE1 0.0790569415042094833f  // 1/sqrt(160)
#define SCALE2 0.0721687836487032206f  // 1/sqrt(192)
#define SQRT2F 1.41421356237309515f

// fragment region: half8 entries (16B each). tile entry = (mt*Kt+kt)*64+lane
#define FE_L1 0      // Mt=2, Kt=2 -> 4*64
#define FE_L2 256    // Mt=2, Kt=4 -> 8*64
#define FE_L3 768    // Mt=2, Kt=4 -> 8*64
#define FE_L4 1280   // Mt=1, Kt=4 -> 4*64 (rows j>=4 zeroed)
#define OFF_CB1 6144   // [8][64] fp32 cond bias (incl b1)
#define OFF_CB2 6656
#define OFF_CB3 7168
#define OFF_CB4 7680   // [8][4]

__global__ __launch_bounds__(256) void prep_kernel(
    const float* __restrict__ c, const float* __restrict__ fu,
    const float* __restrict__ w1, const float* __restrict__ b1,
    const float* __restrict__ w2, const float* __restrict__ b2,
    const float* __restrict__ w3, const float* __restrict__ b3,
    const float* __restrict__ w4, const float* __restrict__ b4,
    float* __restrict__ ws)
{
  int t = blockIdx.x * 256 + threadIdx.x;
  if (t < 12288) {
    // weight A-fragment packing, f16
    _Float16* fr = (_Float16*)ws;
    int e, Ktm;
    const float* w; float scale; int stride; bool perm;
    if (t < 2048)       { e = t;         Ktm = 2; w = w1; scale = SCALE1;          stride = 160; perm = false; }
    else if (t < 6144)  { e = t - 2048;  Ktm = 4; w = w2; scale = SCALE2 * SQRT2F; stride = 192; perm = true;  }
    else if (t < 10240) { e = t - 6144;  Ktm = 4; w = w3; scale = SCALE2 * SQRT2F; stride = 192; perm = true;  }
    else                { e = t - 10240; Ktm = 4; w = w4; scale = SCALE2 * SQRT2F; stride = 192; perm = true;  }
    int til  = e >> 9;           // (mt*Kt+kt)
    int lane = (e >> 3) & 63;
    int r    = e & 7;            // reg within half8
    int q    = lane >> 5;
    int mt = til / Ktm, kt = til - mt * Ktm;
    int j = 32 * mt + (lane & 31);
    int k;
    if (perm) {
      k = 32 * (kt >> 1) + 16 * (kt & 1) + 8 * (r >> 2) + 4 * q + (r & 3);
    } else {
      k = 16 * kt + 8 * q + r;   // layer-1 embedding order (identity)
    }
    float val;
    if (t < 2048) {
      float mw = (fu[0] - (float)((k >> 2) + 1) * (1.0f / 9.0f)) * 9.0f;
      mw = fminf(fmaxf(mw, 0.0f), 1.0f);
      val = w[j * stride + k] * scale * mw;
    } else if (t >= 10240) {
      val = (j < 4) ? w[j * stride + k] * scale : 0.0f;  // mt==0 only
    } else {
      val = w[j * stride + k] * scale;
    }
    fr[t] = (_Float16)val;
  } else if (t < 12288 + 2048) {
    // per-(batch, output) conditioning dot products (fp32), wave-uniform
    int u = t - 12288;
    int grp = u >> 9;
    const float* wr; float bias; float scale; int outoff;
    int b, j;
    if (grp < 3) {
      b = (u & 511) >> 6; j = u & 63;
      if (grp == 0)      { wr = w1 + j * 160 + 32; bias = b1[j]; scale = SCALE1; outoff = OFF_CB1 + b * 64 + j; }
      else if (grp == 1) { wr = w2 + j * 192 + 64; bias = b2[j]; scale = SCALE2; outoff = OFF_CB2 + b * 64 + j; }
      else               { wr = w3 + j * 192 + 64; bias = b3[j]; scale = SCALE2; outoff = OFF_CB3 + b * 64 + j; }
    } else {
      int u2 = u - 1536;
      if (u2 >= 32) return;
      b = u2 >> 2; j = u2 & 3;
      wr = w4 + j * 192 + 64; bias = b4[j]; scale = SCALE2; outoff = OFF_CB4 + b * 4 + j;
    }
    const float4* wv = (const float4*)wr;
    const float4* cv = (const float4*)(c + b * 128);
    float4 s = make_float4(0.f, 0.f, 0.f, 0.f);
    #pragma unroll
    for (int k = 0; k < 32; ++k) {
      float4 a = wv[k], d = cv[k];
      s.x = fmaf(a.x, d.x, s.x);
      s.y = fmaf(a.y, d.y, s.y);
      s.z = fmaf(a.z, d.z, s.z);
      s.w = fmaf(a.w, d.w, s.w);
    }
    float dot = (s.x + s.y) + (s.z + s.w);
    ws[outoff] = fmaf(scale, dot, bias);
  }
}

__global__ __launch_bounds__(256, 4) void decoder_main(
    const float2* __restrict__ coords, const float* __restrict__ ws,
    float4* __restrict__ out)
{
  const int lane = threadIdx.x & 63;
  const int wave = threadIdx.x >> 6;
  const int base = blockIdx.x * 256 + wave * 64;  // 64 px per wave
  const int b    = base >> 16;                    // batch image (block-uniform)
  const int col  = lane & 31;
  const bool hi  = lane >= 32;                    // q = lane>>5
  const int q4   = hi ? 4 : 0;

  const half8* __restrict__ frags = (const half8*)ws;
  const float* __restrict__ cb1 = ws + OFF_CB1 + b * 64;
  const float* __restrict__ cb2 = ws + OFF_CB2 + b * 64;
  const float* __restrict__ cb3 = ws + OFF_CB3 + b * 64;
  const float* __restrict__ cb4 = ws + OFF_CB4 + b * 4;

  const int p0 = base + col, p1 = base + 32 + col;
  const float2 cc0 = coords[p0];
  const float2 cc1 = coords[p1];

  // ---- layer-1 B fragments: sinusoidal embedding via double-angle chain --
  // lane needs freqs f_start+{0,1,4,5}, f_start=2q: 2 transcendentals +
  // 5 doublings per axis-pixel. s'=2sc, c'=(c-s)(c+s).
  half8 bf[2][2];  // [nt][kt]
  {
    const float qm = hi ? 0.4f : 0.1f;  // 0.1 * 2^(2q)
    auto chain = [](float a, float* s, float* c) {
      float s0 = __sinf(a), c0 = __cosf(a);
      s[0] = s0; c[0] = c0;
      float s1 = 2.f * s0 * c0, c1 = (c0 - s0) * (c0 + s0);
      s[1] = s1; c[1] = c1;
      float s2 = 2.f * s1 * c1, c2 = (c1 - s1) * (c1 + s1);
      float s3 = 2.f * s2 * c2, c3 = (c2 - s2) * (c2 + s2);
      float s4 = 2.f * s3 * c3, c4 = (c3 - s3) * (c3 + s3);
      s[2] = s4; c[2] = c4;
      float s5 = 2.f * s4 * c4, c5 = (c4 - s4) * (c4 + s4);
      s[3] = s5; c[3] = c5;
    };
    #pragma unroll
    for (int nt = 0; nt < 2; ++nt) {
      const float2 cc = nt ? cc1 : cc0;
      float sx[4], cx[4], sy[4], cy[4];
      chain(cc.x * qm, sx, cx);
      chain(cc.y * qm, sy, cy);
      #pragma unroll
      for (int kt = 0; kt < 2; ++kt)
        #pragma unroll
        for (int r = 0; r < 8; ++r) {
          const int idx = 2 * kt + (r >> 2);
          float v;
          if      ((r & 3) == 0) v = sx[idx];
          else if ((r & 3) == 1) v = sy[idx];
          else if ((r & 3) == 2) v = cx[idx];
          else                   v = cy[idx];
          bf[nt][kt][r] = (_Float16)v;
        }
    }
  }

  f32x16 acc[2][2];  // [mt][nt]
  half8 nbf[2][4];   // [nt][kt]

  // transition: pkrtz raw acc -> packed-f16 lrelu (pk_mul + pk_max)
  auto transition = [&]() {
    #pragma unroll
    for (int mt = 0; mt < 2; ++mt)
      #pragma unroll
      for (int nt = 0; nt < 2; ++nt) {
        #pragma unroll
        for (int h = 0; h < 2; ++h) {
          half2v pp[4];
          #pragma unroll
          for (int p = 0; p < 4; ++p) {
            fp16x2 t = __builtin_amdgcn_cvt_pkrtz(acc[mt][nt][8 * h + 2 * p],
                                                  acc[mt][nt][8 * h + 2 * p + 1]);
            pp[p] = __builtin_bit_cast(half2v, t);
          }
          half4v q0 = __builtin_shufflevector(pp[0], pp[1], 0, 1, 2, 3);
          half4v q1 = __builtin_shufflevector(pp[2], pp[3], 0, 1, 2, 3);
          half8 f = __builtin_shufflevector(q0, q1, 0, 1, 2, 3, 4, 5, 6, 7);
          half8 f2 = f * (_Float16)0.2f;           // v_pk_mul_f16
          nbf[nt][2 * mt + h] = __builtin_elementwise_max(f, f2);  // v_pk_max_f16
        }
      }
  };

  auto init_acc = [&](const float* __restrict__ cb) {
    #pragma unroll
    for (int mt = 0; mt < 2; ++mt)
      #pragma unroll
      for (int g = 0; g < 4; ++g) {
        const float4 f = *(const float4*)(cb + 32 * mt + 8 * g + q4);
        acc[mt][0][4 * g + 0] = f.x; acc[mt][1][4 * g + 0] = f.x;
        acc[mt][0][4 * g + 1] = f.y; acc[mt][1][4 * g + 1] = f.y;
        acc[mt][0][4 * g + 2] = f.z; acc[mt][1][4 * g + 2] = f.z;
        acc[mt][0][4 * g + 3] = f.w; acc[mt][1][4 * g + 3] = f.w;
      }
  };

  // ---- layer 1: K=32 (Kt=2) ----
  init_acc(cb1);
  #pragma unroll
  for (int kt = 0; kt < 2; ++kt) {
    half8 a0 = frags[FE_L1 + (0 * 2 + kt) * 64 + lane];
    half8 a1 = frags[FE_L1 + (1 * 2 + kt) * 64 + lane];
    acc[0][0] = __builtin_amdgcn_mfma_f32_32x32x16_f16(a0, bf[0][kt], acc[0][0], 0, 0, 0);
    acc[0][1] = __builtin_amdgcn_mfma_f32_32x32x16_f16(a0, bf[1][kt], acc[0][1], 0, 0, 0);
    acc[1][0] = __builtin_amdgcn_mfma_f32_32x32x16_f16(a1, bf[0][kt], acc[1][0], 0, 0, 0);
    acc[1][1] = __builtin_amdgcn_mfma_f32_32x32x16_f16(a1, bf[1][kt], acc[1][1], 0, 0, 0);
  }
  transition();

  // ---- layers 2,3: K=64 (Kt=4) ----
  #pragma unroll
  for (int layer = 0; layer < 2; ++layer) {
    const int fe = layer == 0 ? FE_L2 : FE_L3;
    init_acc(layer == 0 ? cb2 : cb3);
    #pragma unroll
    for (int kt = 0; kt < 4; ++kt) {
      half8 a0 = frags[fe + (0 * 4 + kt) * 64 + lane];
      half8 a1 = frags[fe + (1 * 4 + kt) * 64 + lane];
      acc[0][0] = __builtin_amdgcn_mfma_f32_32x32x16_f16(a0, nbf[0][kt], acc[0][0], 0, 0, 0);
      acc[0][1] = __builtin_amdgcn_mfma_f32_32x32x16_f16(a0, nbf[1][kt], acc[0][1], 0, 0, 0);
      acc[1][0] = __builtin_amdgcn_mfma_f32_32x32x16_f16(a1, nbf[0][kt], acc[1][0], 0, 0, 0);
      acc[1][1] = __builtin_amdgcn_mfma_f32_32x32x16_f16(a1, nbf[1][kt], acc[1][1], 0, 0, 0);
    }
    transition();
  }

  // ---- layer 4: 64 -> 4 ----
  f32x16 acc4[2];
  {
    const float c0 = cb4[0], c1 = cb4[1], c2 = cb4[2], c3 = cb4[3];
    #pragma unroll
    for (int r = 0; r < 16; ++r) { acc4[0][r] = 0.f; acc4[1][r] = 0.f; }
    if (!hi) {
      acc4[0][0] = c0; acc4[0][1] = c1; acc4[0][2] = c2; acc4[0][3] = c3;
      acc4[1][0] = c0; acc4[1][1] = c1; acc4[1][2] = c2; acc4[1][3] = c3;
    }
  }
  #pragma unroll
  for (int kt = 0; kt < 4; ++kt) {
    half8 a0 = frags[FE_L4 + kt * 64 + lane];
    acc4[0] = __builtin_amdgcn_mfma_f32_32x32x16_f16(a0, nbf[0][kt], acc4[0], 0, 0, 0);
    acc4[1] = __builtin_amdgcn_mfma_f32_32x32x16_f16(a0, nbf[1][kt], acc4[1], 0, 0, 0);
  }

  // epilogue: lanes 0..31 hold channels j=0..3 in regs 0..3
  if (!hi) {
    #pragma unroll
    for (int nt = 0; nt < 2; ++nt) {
      const float2 cc = nt ? cc1 : cc0;
      const float rad = sqrtf(cc.x * cc.x + cc.y * cc.y);
      const float tt = fmaxf(rad - 1.0f, 0.0f);
      const float m = 2.0f / (__expf(2.0f * tt) + 1.0f);
      out[nt ? p1 : p0] = make_float4(acc4[nt][0] * m, acc4[nt][1] * m,
                                      acc4[nt][2] * m, acc4[nt][3] * m);
    }
  }
}

extern "C" void kernel_launch(void* const* d_in, const int* in_sizes, int n_in,
                              void* d_out, int out_size, void* d_ws, size_t ws_size,
                              hipStream_t stream) {
  const float* coords = (const float*)d_in[0];
  const float* c      = (const float*)d_in[1];
  const float* fu     = (const float*)d_in[2];
  const float* w1     = (const float*)d_in[3];
  const float* b1     = (const float*)d_in[4];
  const float* w2     = (const float*)d_in[5];
  const float* b2     = (const float*)d_in[6];
  const float* w3     = (const float*)d_in[7];
  const float* b3     = (const float*)d_in[8];
  const float* w4     = (const float*)d_in[9];
  const float* b4     = (const float*)d_in[10];
  float* ws  = (float*)d_ws;
  float* out = (float*)d_out;

  int npix = in_sizes[0] / 2;  // 8*256*256 = 524288

  prep_kernel<<<56, 256, 0, stream>>>(c, fu, w1, b1, w2, b2, w3, b3, w4, b4, ws);
  decoder_main<<<npix / 256, 256, 0, stream>>>(
      (const float2*)coords, ws, (float4*)out);
}